// Round 5
// baseline (414.591 us; speedup 1.0000x reference)
//
#include <hip/hip_runtime.h>
#include <stdint.h>

// Problem constants (fixed by setup_inputs): B=2, C=32, H=W=D=96, N=30000
#define HWD 884736ull          // 96*96*96
#define NV 30000               // vertices per batch
#define AST 1032               // LDS A-tile row stride (shorts): 2064B
#define NBIN 4096              // 2*12^3 = 3456 used, padded to 4096

typedef __attribute__((ext_vector_type(8))) __bf16 bf16x8;
typedef __attribute__((ext_vector_type(4))) float f32x4;
typedef __attribute__((ext_vector_type(2))) float f32x2;
typedef __attribute__((ext_vector_type(4))) unsigned int uint4v;

__device__ __forceinline__ unsigned short f2bf(float f) {
    union { float f; unsigned int u; } v; v.f = f;
    unsigned int u = v.u;
    return (unsigned short)((u + 0x7FFFu + ((u >> 16) & 1u)) >> 16);  // RNE (prep only)
}

// Native HW bf16 convert (RNE) -> compiler emits v_cvt_pk_bf16_f32 pairs
__device__ __forceinline__ unsigned short bfc(float f) {
    __bf16 h = (__bf16)f;
    unsigned short u;
    __builtin_memcpy(&u, &h, 2);
    return u;
}

// Unpack a uint holding two adjacent-channel bf16 values -> float2
__device__ __forceinline__ f32x2 up2(unsigned int u) {
    union { unsigned int u; float f; } lo, hi;
    lo.u = u << 16;
    hi.u = u & 0xFFFF0000u;
    f32x2 r; r.x = lo.f; r.y = hi.f;
    return r;
}

// Per-axis folded 4-wide window weights.
__device__ __forceinline__ void axis_setup(float coord, float sc, int& wstart, float w[3][4]) {
    int i0[3], i1[3];
    float fr[3];
#pragma unroll
    for (int a = 0; a < 3; ++a) {
        float g = coord + (float)(a - 1) * sc;
        float ix = (g + 1.0f) * 0.5f * 95.0f;
        ix = fminf(fmaxf(ix, 0.0f), 95.0f);
        float fl = floorf(ix);
        int x0 = (int)fl;
        i0[a] = x0;
        i1[a] = min(x0 + 1, 95);
        fr[a] = ix - fl;
    }
    int ws = min(max(i0[1] - 1, 0), 92);
    wstart = ws;
#pragma unroll
    for (int a = 0; a < 3; ++a) {
        int d0 = min(max(i0[a] - ws, 0), 3);
        int d1 = min(max(i1[a] - ws, 0), 3);
        float f1 = fr[a], f0 = 1.0f - f1;
#pragma unroll
        for (int j = 0; j < 4; ++j)
            w[a][j] = (d0 == j ? f0 : 0.0f) + (d1 == j ? f1 : 0.0f);
    }
}

// Spatial bin of a vertex: 12^3 cells of 8^3 voxels, batch-separated.
__device__ __forceinline__ int bin_of(const float* __restrict__ verts, int v) {
    float x = verts[(size_t)v * 3 + 0];
    float y = verts[(size_t)v * 3 + 1];
    float z = verts[(size_t)v * 3 + 2];
    float ix = fminf(fmaxf((x + 1.0f) * 0.5f * 95.0f, 0.0f), 95.0f);
    float iy = fminf(fmaxf((y + 1.0f) * 0.5f * 95.0f, 0.0f), 95.0f);
    float iz = fminf(fmaxf((z + 1.0f) * 0.5f * 95.0f, 0.0f), 95.0f);
    int cx = ((int)ix) >> 3;   // 0..11
    int cy = ((int)iy) >> 3;
    int cz = ((int)iz) >> 3;
    int b = (v >= NV) ? 1 : 0;
    return ((b * 12 + cz) * 12 + cy) * 12 + cx;   // < 3456
}

__global__ __launch_bounds__(256) void zero_bins_kernel(unsigned int* __restrict__ cur) {
    cur[blockIdx.x * 256 + threadIdx.x] = 0u;      // grid 16 -> 4096
}

__global__ __launch_bounds__(256) void bin_count_kernel(const float* __restrict__ verts,
                                                        unsigned int* __restrict__ cur) {
    int v = blockIdx.x * 256 + threadIdx.x;
    if (v < 2 * NV) atomicAdd(&cur[bin_of(verts, v)], 1u);
}

// Exclusive prefix over 4096 bins, single block. Leaves bin start cursors in cur.
__global__ __launch_bounds__(256) void scan_kernel(unsigned int* __restrict__ cur) {
    __shared__ unsigned int s[NBIN];
    __shared__ unsigned int w[256];
    int tid = threadIdx.x;
#pragma unroll
    for (int i = 0; i < 16; ++i) s[i * 256 + tid] = cur[i * 256 + tid];
    __syncthreads();
    unsigned int loc[16];
    unsigned int sum = 0;
#pragma unroll
    for (int i = 0; i < 16; ++i) { loc[i] = sum; sum += s[tid * 16 + i]; }
    w[tid] = sum;
    __syncthreads();
    if (tid == 0) {
        unsigned int a = 0;
        for (int j = 0; j < 256; ++j) { unsigned int t = w[j]; w[j] = a; a += t; }
    }
    __syncthreads();
    unsigned int base = w[tid];
#pragma unroll
    for (int i = 0; i < 16; ++i) cur[tid * 16 + i] = base + loc[i];
}

__global__ __launch_bounds__(256) void scatter_kernel(const float* __restrict__ verts,
                                                      unsigned int* __restrict__ cur,
                                                      int* __restrict__ perm) {
    int v = blockIdx.x * 256 + threadIdx.x;
    if (v < 2 * NV) {
        unsigned int pos = atomicAdd(&cur[bin_of(verts, v)], 1u);
        perm[pos] = v;
    }
}

// Pack conv_w (32,32,1,27) fp32 -> bf16 B-fragments for mfma_f32_16x16x32_bf16.
// Layout (verified): element j of wp[(s*2+t)*64 + lane] is
// B[k = s*32 + (lane>>4)*8 + j][o = t*16 + (lane&15)]
__global__ __launch_bounds__(256) void prep_kernel(const float* __restrict__ cw,
                                                   unsigned short* __restrict__ Wp) {
    int gid = blockIdx.x * 256 + threadIdx.x;  // 0..32767
    int j = gid & 7;
    int l = (gid >> 3) & 63;
    int t = (gid >> 9) & 1;
    int s = gid >> 10;
    int kk = ((l >> 4) & 3) * 8 + j;
    int o = t * 16 + (l & 15);
    float v = 0.0f;
    if (kk < 27) v = cw[(size_t)o * 864 + s * 27 + kk];
    Wp[gid] = f2bf(v);
}

// (B,C,H,W,D) fp32 -> (B,H,W,D,C) bf16, LDS-staged for wide coalesced IO.
// (unchanged — near its BW floor)
__global__ __launch_bounds__(256) void transpose_kernel(const float* __restrict__ vox,
                                                        unsigned short* __restrict__ voxT) {
    __shared__ unsigned short T[192 * 40];     // 15.4 KB
    int blk = blockIdx.x;                      // 0..9215 encodes (b, z, y2)
    int tid = threadIdx.x;
    int b = blk / 4608;
    int zy = blk - b * 4608;                   // z*48 + y2
    const float* src = vox + (size_t)b * 32 * HWD + (size_t)zy * 192;
    int c = tid >> 3;                          // 0..31
    int xs = tid & 7;                          // x4 slot within 8-lane group
    const float* srcc = src + (size_t)c * HWD;
#pragma unroll
    for (int i = 0; i < 6; ++i) {
        int x4 = xs + 8 * i;                   // 0..47
        f32x4 v = *(const f32x4*)(srcc + x4 * 4);
#pragma unroll
        for (int k = 0; k < 4; ++k)
            T[(x4 * 4 + k) * 40 + c] = bfc(v[k]);
    }
    __syncthreads();
    unsigned short* dst = voxT + (size_t)blk * 6144;
#pragma unroll
    for (int i = 0; i < 3; ++i) {
        int q = i * 256 + tid;                 // 0..767 (16B chunks)
        int x = q >> 2;
        int cg = (q & 3) * 8;
        uint4v val = *(const uint4v*)&T[x * 40 + cg];
        *(uint4v*)(dst + q * 8) = val;
    }
}

// Fused sample + GEMM (round-2 body) + binned vertex permutation + chunked
// XCD block mapping. A block's 16 vertices come from one spatial cell, and
// consecutive blocks (same cell run) land on the same XCD -> the cell's ~85KB
// window union stays L2-resident instead of random L3/HBM.
__global__ __launch_bounds__(256) void fused_kernel(const unsigned short* __restrict__ voxT,
                                                    const float* __restrict__ verts,
                                                    const int* __restrict__ perm,
                                                    const unsigned short* __restrict__ Wp,
                                                    const float* __restrict__ bias,
                                                    float* __restrict__ out) {
    __shared__ unsigned short At[16 * AST];
    __shared__ int sh_ids[16];
    // Bijective chunked XCD mapping (m204): 3750 blocks, 8 XCDs, q=468, r=6.
    int pb = (int)blockIdx.x;
    int xcd = pb & 7;
    int idx = pb >> 3;
    int lblk = (xcd < 6) ? xcd * 469 + idx : 6 * 469 + (xcd - 6) * 468 + idx;

    int tid = threadIdx.x;
    int vl = tid >> 4;               // 0..15 vertex in block
    int cp = tid & 15;               // channel pair: channels {2cp, 2cp+1}
    int vg = perm[lblk * 16 + vl];   // binned vertex id, 0..59999
    if (cp == 0) sh_ids[vl] = vg;

    const float* vp = verts + (size_t)vg * 3;
    float vx = vp[0], vy = vp[1], vz = vp[2];
    const float sc = 2.0f / 95.0f;
    int wsx, wsy, wsz;
    float wx[3][4], wy[3][4], wz[3][4];
    axis_setup(vx, sc, wsx, wx);  // x -> D axis (innermost spatial)
    axis_setup(vy, sc, wsy, wy);  // y -> W axis
    axis_setup(vz, sc, wsz, wz);  // z -> H axis
    int bb = (vg >= NV) ? 1 : 0;
    const unsigned short* vb = voxT + (size_t)bb * HWD * 32 + 2 * cp;

    f32x2 zz = {0.f, 0.f};
    f32x2 f[27];
#pragma unroll
    for (int k = 0; k < 27; ++k) f[k] = zz;

#pragma unroll
    for (int tz = 0; tz < 4; ++tz) {
        f32x2 ry[3][3];
#pragma unroll
        for (int bq = 0; bq < 3; ++bq)
#pragma unroll
            for (int a = 0; a < 3; ++a) ry[bq][a] = zz;
#pragma unroll
        for (int ty = 0; ty < 4; ++ty) {
            const unsigned short* row =
                vb + (((size_t)(wsz + tz) * 96 + (size_t)(wsy + ty)) * 96 + wsx) * 32;
            unsigned int u0 = *(const unsigned int*)(row);
            unsigned int u1 = *(const unsigned int*)(row + 32);
            unsigned int u2 = *(const unsigned int*)(row + 64);
            unsigned int u3 = *(const unsigned int*)(row + 96);
            f32x2 b0 = up2(u0), b1 = up2(u1), b2 = up2(u2), b3 = up2(u3);
#pragma unroll
            for (int a = 0; a < 3; ++a) {
                f32x2 r = b0 * wx[a][0] + b1 * wx[a][1] + b2 * wx[a][2] + b3 * wx[a][3];
#pragma unroll
                for (int bq = 0; bq < 3; ++bq)
                    ry[bq][a] += r * wy[bq][ty];
            }
        }
#pragma unroll
        for (int g = 0; g < 3; ++g)
#pragma unroll
            for (int bq = 0; bq < 3; ++bq)
#pragma unroll
                for (int a = 0; a < 3; ++a)
                    f[9 * a + 3 * bq + g] += wz[g][tz] * ry[bq][a];
    }

    // Pack both channels' 27 taps (+5 zero pad) to bf16 pairs (HW cvt_pk).
    unsigned int pk0[16], pk1[16];
#pragma unroll
    for (int i = 0; i < 16; ++i) {
        float l0 = (2 * i < 27) ? f[2 * i].x : 0.0f;
        float h0 = (2 * i + 1 < 27) ? f[2 * i + 1].x : 0.0f;
        float l1 = (2 * i < 27) ? f[2 * i].y : 0.0f;
        float h1 = (2 * i + 1 < 27) ? f[2 * i + 1].y : 0.0f;
        pk0[i] = (unsigned int)bfc(l0) | ((unsigned int)bfc(h0) << 16);
        pk1[i] = (unsigned int)bfc(l1) | ((unsigned int)bfc(h1) << 16);
    }
    // Chunk k (16B) of this lane's 64-short region goes to slot (k ^ (cp&7)) —
    // balanced LDS banks; the GEMM read side undoes the swizzle.
    unsigned short* abase = &At[vl * AST + cp * 64];
    int e = cp & 7;
    {
        uint4v c0 = {pk0[0], pk0[1], pk0[2], pk0[3]};
        uint4v c1 = {pk0[4], pk0[5], pk0[6], pk0[7]};
        uint4v c2 = {pk0[8], pk0[9], pk0[10], pk0[11]};
        uint4v c3 = {pk0[12], pk0[13], pk0[14], pk0[15]};
        uint4v c4 = {pk1[0], pk1[1], pk1[2], pk1[3]};
        uint4v c5 = {pk1[4], pk1[5], pk1[6], pk1[7]};
        uint4v c6 = {pk1[8], pk1[9], pk1[10], pk1[11]};
        uint4v c7 = {pk1[12], pk1[13], pk1[14], pk1[15]};
        *(uint4v*)(abase + ((0 ^ e) << 3)) = c0;
        *(uint4v*)(abase + ((1 ^ e) << 3)) = c1;
        *(uint4v*)(abase + ((2 ^ e) << 3)) = c2;
        *(uint4v*)(abase + ((3 ^ e) << 3)) = c3;
        *(uint4v*)(abase + ((4 ^ e) << 3)) = c4;
        *(uint4v*)(abase + ((5 ^ e) << 3)) = c5;
        *(uint4v*)(abase + ((6 ^ e) << 3)) = c6;
        *(uint4v*)(abase + ((7 ^ e) << 3)) = c7;
    }

    __syncthreads();

    int wv = tid >> 6;               // wave id 0..3; waves 0,1 do the GEMM
    if (wv < 2) {
        int lane = tid & 63;
        int mrow = lane & 15, quad = lane >> 4;
        const bf16x8* wp = (const bf16x8*)Wp;
        f32x4 acc = {0.f, 0.f, 0.f, 0.f};
#pragma unroll 8
        for (int s = 0; s < 32; ++s) {
            int cpg = s >> 1;
            int kk = ((s & 1) << 2) | quad;
            bf16x8 a = *(const bf16x8*)&At[mrow * AST + cpg * 64 + ((kk ^ (cpg & 7)) << 3)];
            bf16x8 b = wp[(s * 2 + wv) * 64 + lane];
            acc = __builtin_amdgcn_mfma_f32_16x16x32_bf16(a, b, acc, 0, 0, 0);
        }
        float bs = bias[wv * 16 + mrow];
#pragma unroll
        for (int r = 0; r < 4; ++r) {
            int v = sh_ids[quad * 4 + r];
            out[(size_t)v * 32 + wv * 16 + mrow] = acc[r] + bs;
        }
    }
}

extern "C" void kernel_launch(void* const* d_in, const int* in_sizes, int n_in,
                              void* d_out, int out_size, void* d_ws, size_t ws_size,
                              hipStream_t stream) {
    const float* vox = (const float*)d_in[0];
    const float* verts = (const float*)d_in[1];
    const float* cw = (const float*)d_in[2];
    const float* cb = (const float*)d_in[3];
    float* out = (float*)d_out;

    // ws layout: Wp (64 KB) | voxT bf16 (113.25 MB) | cur (16 KB) | perm (240 KB)
    unsigned short* Wp = (unsigned short*)d_ws;
    unsigned short* voxT = (unsigned short*)((char*)d_ws + 65536);
    char* tail = (char*)d_ws + 65536 + 2ull * HWD * 32 * 2;
    unsigned int* cur = (unsigned int*)tail;
    int* perm = (int*)(tail + NBIN * 4);

    hipLaunchKernelGGL(zero_bins_kernel, dim3(16), dim3(256), 0, stream, cur);
    hipLaunchKernelGGL(bin_count_kernel, dim3(235), dim3(256), 0, stream, verts, cur);
    hipLaunchKernelGGL(scan_kernel, dim3(1), dim3(256), 0, stream, cur);
    hipLaunchKernelGGL(scatter_kernel, dim3(235), dim3(256), 0, stream, verts, cur, perm);
    hipLaunchKernelGGL(prep_kernel, dim3(128), dim3(256), 0, stream, cw, Wp);
    hipLaunchKernelGGL(transpose_kernel, dim3(9216), dim3(256), 0, stream, vox, voxT);
    hipLaunchKernelGGL(fused_kernel, dim3(3750), dim3(256), 0, stream,
                       voxT, verts, perm, Wp, cb, out);
}

// Round 6
// 384.656 us; speedup vs baseline: 1.0778x; 1.0778x over previous
//
#include <hip/hip_runtime.h>
#include <stdint.h>

// Problem constants (fixed by setup_inputs): B=2, C=32, H=W=D=96, N=30000
#define HWD 884736ull          // 96*96*96
#define NV 30000               // vertices per batch
#define AST 1032               // LDS A-tile row stride (shorts): 2064B

typedef __attribute__((ext_vector_type(8))) __bf16 bf16x8;
typedef __attribute__((ext_vector_type(4))) float f32x4;
typedef __attribute__((ext_vector_type(2))) float f32x2;
typedef __attribute__((ext_vector_type(4))) unsigned int uint4v;

__device__ __forceinline__ unsigned short f2bf(float f) {
    union { float f; unsigned int u; } v; v.f = f;
    unsigned int u = v.u;
    return (unsigned short)((u + 0x7FFFu + ((u >> 16) & 1u)) >> 16);  // RNE (prep only)
}

// Native HW bf16 convert (RNE) -> compiler emits v_cvt_pk_bf16_f32 pairs
__device__ __forceinline__ unsigned short bfc(float f) {
    __bf16 h = (__bf16)f;
    unsigned short u;
    __builtin_memcpy(&u, &h, 2);
    return u;
}

// Unpack a uint holding two adjacent-channel bf16 values -> float2
__device__ __forceinline__ f32x2 up2(unsigned int u) {
    union { unsigned int u; float f; } lo, hi;
    lo.u = u << 16;
    hi.u = u & 0xFFFF0000u;
    f32x2 r; r.x = lo.f; r.y = hi.f;
    return r;
}

// Per-axis folded 4-wide window weights.
__device__ __forceinline__ void axis_setup(float coord, float sc, int& wstart, float w[3][4]) {
    int i0[3], i1[3];
    float fr[3];
#pragma unroll
    for (int a = 0; a < 3; ++a) {
        float g = coord + (float)(a - 1) * sc;
        float ix = (g + 1.0f) * 0.5f * 95.0f;
        ix = fminf(fmaxf(ix, 0.0f), 95.0f);
        float fl = floorf(ix);
        int x0 = (int)fl;
        i0[a] = x0;
        i1[a] = min(x0 + 1, 95);
        fr[a] = ix - fl;
    }
    int ws = min(max(i0[1] - 1, 0), 92);
    wstart = ws;
#pragma unroll
    for (int a = 0; a < 3; ++a) {
        int d0 = min(max(i0[a] - ws, 0), 3);
        int d1 = min(max(i1[a] - ws, 0), 3);
        float f1 = fr[a], f0 = 1.0f - f1;
#pragma unroll
        for (int j = 0; j < 4; ++j)
            w[a][j] = (d0 == j ? f0 : 0.0f) + (d1 == j ? f1 : 0.0f);
    }
}

// Combined transpose + weight-prep kernel (saves one launch, ~4-5us of
// measured per-launch tax in this harness).
// Blocks [0, 9216): (B,C,H,W,D) fp32 -> (B,H,W,D,C) bf16, LDS-staged.
//   Phase 1: each 8-lane group reads 128B contiguous from one channel row,
//   converts to bf16, scatters into LDS T[x][c] (stride 40, bank-clean).
//   Phase 2: each lane stores 16B (8 consecutive channels of one x), fully
//   coalesced dwordx4 stores.
// Blocks [9216, 9344): pack conv_w (32,32,1,27) fp32 -> bf16 B-fragments for
//   mfma_f32_16x16x32_bf16. Layout (verified): element j of
//   wp[(s*2+t)*64 + lane] is B[k = s*32 + (lane>>4)*8 + j][o = t*16 + (lane&15)]
__global__ __launch_bounds__(256) void transpose_prep_kernel(const float* __restrict__ vox,
                                                             unsigned short* __restrict__ voxT,
                                                             const float* __restrict__ cw,
                                                             unsigned short* __restrict__ Wp) {
    __shared__ unsigned short T[192 * 40];     // 15.4 KB
    int blk = blockIdx.x;
    int tid = threadIdx.x;
    if (blk >= 9216) {                         // prep path (block-uniform branch)
        int gid = (blk - 9216) * 256 + tid;    // 0..32767
        int j = gid & 7;
        int l = (gid >> 3) & 63;
        int t = (gid >> 9) & 1;
        int s = gid >> 10;
        int kk = ((l >> 4) & 3) * 8 + j;
        int o = t * 16 + (l & 15);
        float v = 0.0f;
        if (kk < 27) v = cw[(size_t)o * 864 + s * 27 + kk];
        Wp[gid] = f2bf(v);
        return;
    }
    int b = blk / 4608;
    int zy = blk - b * 4608;                   // z*48 + y2
    const float* src = vox + (size_t)b * 32 * HWD + (size_t)zy * 192;
    int c = tid >> 3;                          // 0..31
    int xs = tid & 7;                          // x4 slot within 8-lane group
    const float* srcc = src + (size_t)c * HWD;
#pragma unroll
    for (int i = 0; i < 6; ++i) {
        int x4 = xs + 8 * i;                   // 0..47
        f32x4 v = *(const f32x4*)(srcc + x4 * 4);
#pragma unroll
        for (int k = 0; k < 4; ++k)
            T[(x4 * 4 + k) * 40 + c] = bfc(v[k]);
    }
    __syncthreads();
    unsigned short* dst = voxT + (size_t)blk * 6144;
#pragma unroll
    for (int i = 0; i < 3; ++i) {
        int q = i * 256 + tid;                 // 0..767 (16B chunks)
        int x = q >> 2;
        int cg = (q & 3) * 8;
        uint4v val = *(const uint4v*)&T[x * 40 + cg];
        *(uint4v*)(dst + q * 8) = val;
    }
}

// Fused sample + GEMM (round-2 body, best measured) with per-tz-slab load
// hoisting: all 16 row loads of a z-slab are issued before any unpack/math,
// quadrupling per-thread VMEM parallelism (+12 VGPR). Block = 256 threads =
// 16 vertices x 16 channel-pairs; each lane gathers two adjacent channels
// (uint loads; 16 cp-lanes of a vertex cover one full 64B line per x-offset).
// A-tile writes use the XOR swizzle (k ^ (cp&7)); the GEMM read undoes it.
// Waves 0/1 run the 16x1024 @ 1024x32 MFMA GEMM and write out with bias.
__global__ __launch_bounds__(256) void fused_kernel(const unsigned short* __restrict__ voxT,
                                                    const float* __restrict__ verts,
                                                    const unsigned short* __restrict__ Wp,
                                                    const float* __restrict__ bias,
                                                    float* __restrict__ out) {
    __shared__ unsigned short At[16 * AST];
    int tid = threadIdx.x;
    int vl = tid >> 4;               // 0..15 vertex in block
    int cp = tid & 15;               // channel pair: channels {2cp, 2cp+1}
    int vg = (int)blockIdx.x * 16 + vl;   // 3750*16 = 60000 exactly

    const float* vp = verts + (size_t)vg * 3;
    float vx = vp[0], vy = vp[1], vz = vp[2];
    const float sc = 2.0f / 95.0f;
    int wsx, wsy, wsz;
    float wx[3][4], wy[3][4], wz[3][4];
    axis_setup(vx, sc, wsx, wx);  // x -> D axis (innermost spatial)
    axis_setup(vy, sc, wsy, wy);  // y -> W axis
    axis_setup(vz, sc, wsz, wz);  // z -> H axis
    int bb = (vg >= NV) ? 1 : 0;
    const unsigned short* vb = voxT + (size_t)bb * HWD * 32 + 2 * cp;

    f32x2 zz = {0.f, 0.f};
    f32x2 f[27];
#pragma unroll
    for (int k = 0; k < 27; ++k) f[k] = zz;

#pragma unroll
    for (int tz = 0; tz < 4; ++tz) {
        // Hoisted slab loads: 16 independent uint loads in flight.
        unsigned int u[4][4];
#pragma unroll
        for (int ty = 0; ty < 4; ++ty) {
            const unsigned short* row =
                vb + (((size_t)(wsz + tz) * 96 + (size_t)(wsy + ty)) * 96 + wsx) * 32;
            u[ty][0] = *(const unsigned int*)(row);
            u[ty][1] = *(const unsigned int*)(row + 32);
            u[ty][2] = *(const unsigned int*)(row + 64);
            u[ty][3] = *(const unsigned int*)(row + 96);
        }
        f32x2 ry[3][3];
#pragma unroll
        for (int bq = 0; bq < 3; ++bq)
#pragma unroll
            for (int a = 0; a < 3; ++a) ry[bq][a] = zz;
#pragma unroll
        for (int ty = 0; ty < 4; ++ty) {
            f32x2 b0 = up2(u[ty][0]), b1 = up2(u[ty][1]);
            f32x2 b2 = up2(u[ty][2]), b3 = up2(u[ty][3]);
#pragma unroll
            for (int a = 0; a < 3; ++a) {
                f32x2 r = b0 * wx[a][0] + b1 * wx[a][1] + b2 * wx[a][2] + b3 * wx[a][3];
#pragma unroll
                for (int bq = 0; bq < 3; ++bq)
                    ry[bq][a] += r * wy[bq][ty];
            }
        }
#pragma unroll
        for (int g = 0; g < 3; ++g)
#pragma unroll
            for (int bq = 0; bq < 3; ++bq)
#pragma unroll
                for (int a = 0; a < 3; ++a)
                    f[9 * a + 3 * bq + g] += wz[g][tz] * ry[bq][a];
    }

    // Pack both channels' 27 taps (+5 zero pad) to bf16 pairs (HW cvt_pk).
    unsigned int pk0[16], pk1[16];
#pragma unroll
    for (int i = 0; i < 16; ++i) {
        float l0 = (2 * i < 27) ? f[2 * i].x : 0.0f;
        float h0 = (2 * i + 1 < 27) ? f[2 * i + 1].x : 0.0f;
        float l1 = (2 * i < 27) ? f[2 * i].y : 0.0f;
        float h1 = (2 * i + 1 < 27) ? f[2 * i + 1].y : 0.0f;
        pk0[i] = (unsigned int)bfc(l0) | ((unsigned int)bfc(h0) << 16);
        pk1[i] = (unsigned int)bfc(l1) | ((unsigned int)bfc(h1) << 16);
    }
    // Chunk k (16B) of this lane's 64-short region goes to slot (k ^ (cp&7)) —
    // balanced LDS banks; the GEMM read side undoes the swizzle.
    unsigned short* abase = &At[vl * AST + cp * 64];
    int e = cp & 7;
    {
        uint4v c0 = {pk0[0], pk0[1], pk0[2], pk0[3]};
        uint4v c1 = {pk0[4], pk0[5], pk0[6], pk0[7]};
        uint4v c2 = {pk0[8], pk0[9], pk0[10], pk0[11]};
        uint4v c3 = {pk0[12], pk0[13], pk0[14], pk0[15]};
        uint4v c4 = {pk1[0], pk1[1], pk1[2], pk1[3]};
        uint4v c5 = {pk1[4], pk1[5], pk1[6], pk1[7]};
        uint4v c6 = {pk1[8], pk1[9], pk1[10], pk1[11]};
        uint4v c7 = {pk1[12], pk1[13], pk1[14], pk1[15]};
        *(uint4v*)(abase + ((0 ^ e) << 3)) = c0;
        *(uint4v*)(abase + ((1 ^ e) << 3)) = c1;
        *(uint4v*)(abase + ((2 ^ e) << 3)) = c2;
        *(uint4v*)(abase + ((3 ^ e) << 3)) = c3;
        *(uint4v*)(abase + ((4 ^ e) << 3)) = c4;
        *(uint4v*)(abase + ((5 ^ e) << 3)) = c5;
        *(uint4v*)(abase + ((6 ^ e) << 3)) = c6;
        *(uint4v*)(abase + ((7 ^ e) << 3)) = c7;
    }

    __syncthreads();

    int wv = tid >> 6;               // wave id 0..3; waves 0,1 do the GEMM
    if (wv < 2) {
        int lane = tid & 63;
        int mrow = lane & 15, quad = lane >> 4;
        const bf16x8* wp = (const bf16x8*)Wp;
        f32x4 acc = {0.f, 0.f, 0.f, 0.f};
#pragma unroll 8
        for (int s = 0; s < 32; ++s) {
            // Global chunk G = s*4+quad; region cpg = G>>3, local k = G&7,
            // read at slot (k ^ (cpg&7)) to match the swizzled write.
            int cpg = s >> 1;
            int kk = ((s & 1) << 2) | quad;
            bf16x8 a = *(const bf16x8*)&At[mrow * AST + cpg * 64 + ((kk ^ (cpg & 7)) << 3)];
            bf16x8 b = wp[(s * 2 + wv) * 64 + lane];
            acc = __builtin_amdgcn_mfma_f32_16x16x32_bf16(a, b, acc, 0, 0, 0);
        }
        float bs = bias[wv * 16 + mrow];
#pragma unroll
        for (int r = 0; r < 4; ++r) {
            int v = (int)blockIdx.x * 16 + quad * 4 + r;
            out[(size_t)v * 32 + wv * 16 + mrow] = acc[r] + bs;
        }
    }
}

extern "C" void kernel_launch(void* const* d_in, const int* in_sizes, int n_in,
                              void* d_out, int out_size, void* d_ws, size_t ws_size,
                              hipStream_t stream) {
    const float* vox = (const float*)d_in[0];
    const float* verts = (const float*)d_in[1];
    const float* cw = (const float*)d_in[2];
    const float* cb = (const float*)d_in[3];
    float* out = (float*)d_out;

    // ws layout: Wp (64 KB) | voxT bf16 (2*HWD*32*2 = 113.25 MB). Total ~113.4 MB.
    unsigned short* Wp = (unsigned short*)d_ws;
    unsigned short* voxT = (unsigned short*)((char*)d_ws + 65536);

    hipLaunchKernelGGL(transpose_prep_kernel, dim3(9344), dim3(256), 0, stream,
                       vox, voxT, cw, Wp);
    hipLaunchKernelGGL(fused_kernel, dim3(3750), dim3(256), 0, stream,
                       voxT, verts, Wp, cb, out);
}